// Round 1
// baseline (584.216 us; speedup 1.0000x reference)
//
#include <hip/hip_runtime.h>

#define NCLS 19
#define NIMG 16
#define HW (512 * 512)
#define EPSV 1e-6f

// ---------------------------------------------------------------------------
// Kernel 1: per-pixel argmax over C for preds & targets, histogram into
// per-(image,class) counters: pred_cnt, targ_cnt, inter.
// Each thread handles 4 consecutive pixels via float4 loads. For fixed class
// c the (H*W) plane is contiguous -> coalesced 16B/lane loads.
// ---------------------------------------------------------------------------
__global__ __launch_bounds__(256) void hist_kernel(
    const float* __restrict__ preds, const float* __restrict__ targs,
    int* __restrict__ gpred, int* __restrict__ gtarg, int* __restrict__ ginter)
{
    __shared__ int s_pred[NCLS];
    __shared__ int s_targ[NCLS];
    __shared__ int s_inter[NCLS];

    const int t = threadIdx.x;
    if (t < NCLS) { s_pred[t] = 0; s_targ[t] = 0; s_inter[t] = 0; }
    __syncthreads();

    const int n = blockIdx.y;
    const long pix  = (long)blockIdx.x * 1024 + (long)t * 4;   // 4 pixels/thread
    const long base = (long)n * NCLS * HW + pix;

    // ---- argmax over classes for preds (strict > => first-max like jnp.argmax)
    float4 v = *(const float4*)(preds + base);
    float m0 = v.x, m1 = v.y, m2 = v.z, m3 = v.w;
    int   a0 = 0, a1 = 0, a2 = 0, a3 = 0;
#pragma unroll
    for (int c = 1; c < NCLS; ++c) {
        float4 u = *(const float4*)(preds + base + (long)c * HW);
        if (u.x > m0) { m0 = u.x; a0 = c; }
        if (u.y > m1) { m1 = u.y; a1 = c; }
        if (u.z > m2) { m2 = u.z; a2 = c; }
        if (u.w > m3) { m3 = u.w; a3 = c; }
    }

    // ---- argmax over classes for targets
    v = *(const float4*)(targs + base);
    float q0 = v.x, q1 = v.y, q2 = v.z, q3 = v.w;
    int   b0 = 0, b1 = 0, b2 = 0, b3 = 0;
#pragma unroll
    for (int c = 1; c < NCLS; ++c) {
        float4 u = *(const float4*)(targs + base + (long)c * HW);
        if (u.x > q0) { q0 = u.x; b0 = c; }
        if (u.y > q1) { q1 = u.y; b1 = c; }
        if (u.z > q2) { q2 = u.z; b2 = c; }
        if (u.w > q3) { q3 = u.w; b3 = c; }
    }

    // ---- LDS histogram
    atomicAdd(&s_pred[a0], 1); atomicAdd(&s_targ[b0], 1); if (a0 == b0) atomicAdd(&s_inter[a0], 1);
    atomicAdd(&s_pred[a1], 1); atomicAdd(&s_targ[b1], 1); if (a1 == b1) atomicAdd(&s_inter[a1], 1);
    atomicAdd(&s_pred[a2], 1); atomicAdd(&s_targ[b2], 1); if (a2 == b2) atomicAdd(&s_inter[a2], 1);
    atomicAdd(&s_pred[a3], 1); atomicAdd(&s_targ[b3], 1); if (a3 == b3) atomicAdd(&s_inter[a3], 1);
    __syncthreads();

    // ---- one global atomic per bin per block (device-scope, XCD-safe)
    if (t < NCLS) {
        atomicAdd(&gpred [n * NCLS + t], s_pred [t]);
        atomicAdd(&gtarg [n * NCLS + t], s_targ [t]);
        atomicAdd(&ginter[n * NCLS + t], s_inter[t]);
    }
}

// ---------------------------------------------------------------------------
// Kernel 2: IoU per (n,c), weighted mean -> scalar.
// mean(mean(weighted, axis=1)) == sum(weighted) / (N*C) since C is constant.
// ---------------------------------------------------------------------------
__global__ __launch_bounds__(256) void finalize_kernel(
    const int* __restrict__ gpred, const int* __restrict__ gtarg,
    const int* __restrict__ ginter, const float* __restrict__ wts,
    float* __restrict__ out)
{
    const int t = threadIdx.x;
    float sum = 0.f;
    for (int i = t; i < NIMG * NCLS; i += 256) {
        const int c  = i % NCLS;
        const float ic = (float)ginter[i];
        const float un = (float)gpred[i] + (float)gtarg[i] - ic;
        sum += wts[c] * (ic + EPSV) / (un + EPSV);
    }
    // wave64 butterfly reduce
#pragma unroll
    for (int off = 32; off > 0; off >>= 1) sum += __shfl_down(sum, off, 64);

    __shared__ float wsum[4];
    if ((t & 63) == 0) wsum[t >> 6] = sum;
    __syncthreads();
    if (t == 0) {
        out[0] = (wsum[0] + wsum[1] + wsum[2] + wsum[3]) / (float)(NIMG * NCLS);
    }
}

extern "C" void kernel_launch(void* const* d_in, const int* in_sizes, int n_in,
                              void* d_out, int out_size, void* d_ws, size_t ws_size,
                              hipStream_t stream) {
    const float* preds = (const float*)d_in[0];
    const float* targs = (const float*)d_in[1];
    const float* wts   = (const float*)d_in[2];
    float* out = (float*)d_out;

    int* gpred  = (int*)d_ws;
    int* gtarg  = gpred + NIMG * NCLS;
    int* ginter = gtarg + NIMG * NCLS;

    // ws is re-poisoned to 0xAA before every timed launch -> zero it each call.
    hipMemsetAsync(d_ws, 0, 3 * NIMG * NCLS * sizeof(int), stream);

    dim3 grid(HW / 1024, NIMG);  // 256 blocks/image * 16 images = 4096 blocks
    hist_kernel<<<grid, 256, 0, stream>>>(preds, targs, gpred, gtarg, ginter);
    finalize_kernel<<<1, 256, 0, stream>>>(gpred, gtarg, ginter, wts, out);
}